// Round 4
// baseline (125.745 us; speedup 1.0000x reference)
//
#include <hip/hip_runtime.h>
#include <math.h>

// st_VQEmbedding: z [B=16,N=4096,D=64] f32, emb [K=512,D=64] f32
// out = emb[argmin_k (x2 - 2*x.e_k) + e2_k], straight-through (q+x)-x.
// Bit-exact vs rounds 1-3 (all passed absmax 0.0): same FMA chains, same scan
// order, same tie-break (strict <, ascending k).
//
// R4: R3's scalar-pipe design (lane = point, wave = K-quarter, e-rows via
// s_load -> v_fmac v,s,v) + asm-pinned x registers. R3 failed because the
// compiler kept VGPR_Count at 44 and re-loaded x from global inside the
// k-loop (vmem-latency-bound, 96us). The empty asm with "+v" constraints
// makes the x values opaque so they MUST stay in VGPRs (64 regs, fits the
// 128-VGPR budget of __launch_bounds__(256,4)).

constexpr int K     = 512;
constexpr int NPTS  = 16 * 4096;   // 65536 points
constexpr int BLOCK = 256;
constexpr int NW    = 4;           // waves per block
constexpr int PPB   = 64;          // points per block (one per lane)
constexpr int KQ    = K / NW;      // 128 codes per wave

__global__ __launch_bounds__(BLOCK, 4)
void vq_st_kernel(const float* __restrict__ z,
                  const float* __restrict__ emb,
                  float* __restrict__ out)
{
    __shared__ float e2s[K];
    __shared__ float bestw[NW][PPB];
    __shared__ int   bidxw[NW][PPB];
    __shared__ int   bfin[PPB];

    const int tid  = threadIdx.x;
    const int lane = tid & 63;
    // wave id, forced wave-uniform so the k index is scalar-provable -> s_load
    const int w    = __builtin_amdgcn_readfirstlane(tid >> 6);

    const float4* ef4 = reinterpret_cast<const float4*>(emb);
    const float4* zf4 = reinterpret_cast<const float4*>(z);
    float4*       of4 = reinterpret_cast<float4*>(out);

    const int base = blockIdx.x * PPB;

    // ---- e2[k] = sum_d fl(e_kd^2), sequential, unfused (matches jnp) ----
    {
        #pragma clang fp contract(off)
        #pragma unroll
        for (int kk = 0; kk < K / BLOCK; ++kk) {
            const int k = tid + kk * BLOCK;
            const float4* row = ef4 + k * 16;
            float s = 0.0f;
            #pragma unroll
            for (int i = 0; i < 16; ++i) {
                float4 v = row[i];
                s = s + v.x * v.x;
                s = s + v.y * v.y;
                s = s + v.z * v.z;
                s = s + v.w * v.w;
            }
            e2s[k] = s;
        }
    }

    // ---- x row for this lane's point, kept in VGPRs ----
    const int pt = base + lane;
    float4 xv[16];
    #pragma unroll
    for (int i = 0; i < 16; ++i) xv[i] = zf4[pt * 16 + i];

    float x2 = 0.0f;
    {
        #pragma clang fp contract(off)
        #pragma unroll
        for (int i = 0; i < 16; ++i) {
            x2 = x2 + xv[i].x * xv[i].x;
            x2 = x2 + xv[i].y * xv[i].y;
            x2 = x2 + xv[i].z * xv[i].z;
            x2 = x2 + xv[i].w * xv[i].w;
        }
    }

    // PIN x in VGPRs: opaque asm defines new values the compiler cannot
    // rematerialize from the global loads. 64 VGPRs held live through k-loop.
    #pragma unroll
    for (int i = 0; i < 16; ++i) {
        asm volatile("" : "+v"(xv[i].x), "+v"(xv[i].y),
                          "+v"(xv[i].z), "+v"(xv[i].w));
    }

    __syncthreads();   // e2s ready

    // ---- scan this wave's K-quarter; e rows via scalar loads ----
    const int k0 = w * KQ;
    float best = INFINITY;
    int   bi   = 0;

    for (int kk = 0; kk < KQ; kk += 2) {
        const int ka = k0 + kk;
        const int kb = ka + 1;
        const float4* ra = ef4 + ka * 16;   // wave-uniform -> s_load
        const float4* rb = ef4 + kb * 16;
        float a0 = 0.0f, a1 = 0.0f;         // two independent chains (ILP)
        #pragma unroll
        for (int j = 0; j < 16; ++j) {
            const float4 ea = ra[j];
            const float4 eb = rb[j];
            a0 = __builtin_fmaf(xv[j].x, ea.x, a0);
            a0 = __builtin_fmaf(xv[j].y, ea.y, a0);
            a0 = __builtin_fmaf(xv[j].z, ea.z, a0);
            a0 = __builtin_fmaf(xv[j].w, ea.w, a0);
            a1 = __builtin_fmaf(xv[j].x, eb.x, a1);
            a1 = __builtin_fmaf(xv[j].y, eb.y, a1);
            a1 = __builtin_fmaf(xv[j].z, eb.z, a1);
            a1 = __builtin_fmaf(xv[j].w, eb.w, a1);
        }
        // dist = (x2 - 2*dot) + e2 ; e2s[k] is a whole-wave broadcast read
        const float d0 = (x2 - 2.0f * a0) + e2s[ka];
        const float d1 = (x2 - 2.0f * a1) + e2s[kb];
        if (d0 < best) { best = d0; bi = ka; }   // strict <, ascending k
        if (d1 < best) { best = d1; bi = kb; }
    }

    bestw[w][lane] = best;
    bidxw[w][lane] = bi;
    __syncthreads();

    // ---- combine the 4 wave-quarters: ascending wave = ascending k ----
    if (tid < PPB) {
        float b  = bestw[0][tid];
        int   i0 = bidxw[0][tid];
        #pragma unroll
        for (int ww = 1; ww < NW; ++ww) {
            const float ob = bestw[ww][tid];
            const int   oi = bidxw[ww][tid];
            if (ob < b) { b = ob; i0 = oi; }   // strict < keeps lowest k-range
        }
        bfin[tid] = i0;
    }
    __syncthreads();

    // ---- dense epilogue: lane-linear float4 stores ----
    #pragma unroll
    for (int i = 0; i < (PPB * 16) / BLOCK; ++i) {   // 4 iters
        const int idx = i * BLOCK + tid;
        const int p   = idx >> 4;
        const int j   = idx & 15;
        const float4 q = ef4[bfin[p] * 16 + j];
        const float4 x = zf4[(base + p) * 16 + j];
        float4 o;
        o.x = (q.x + x.x) - x.x;
        o.y = (q.y + x.y) - x.y;
        o.z = (q.z + x.z) - x.z;
        o.w = (q.w + x.w) - x.w;
        of4[(base + p) * 16 + j] = o;
    }
}

extern "C" void kernel_launch(void* const* d_in, const int* in_sizes, int n_in,
                              void* d_out, int out_size, void* d_ws, size_t ws_size,
                              hipStream_t stream) {
    const float* z   = (const float*)d_in[0];
    const float* emb = (const float*)d_in[1];
    float* out = (float*)d_out;

    const int grid = NPTS / PPB;   // 1024 blocks -> 4 per CU, 16 waves/CU
    vq_st_kernel<<<grid, BLOCK, 0, stream>>>(z, emb, out);
}

// Round 5
// 82.909 us; speedup vs baseline: 1.5167x; 1.5167x over previous
//
#include <hip/hip_runtime.h>
#include <math.h>

// st_VQEmbedding via MFMA: z [65536,64] f32, emb [512,64] f32.
// dist = (x2 - 2*dot) + e2 with dot computed by bf16 2-term-split MFMA
// (hi*hi + hi*lo + lo*hi in fp32 accum; |err| ~6e-7, far below the ~1.5e-5
// summation-order perturbation the reference already tolerated with zero
// argmin flips in rounds 1-4). x2/e2/final expression/tie-break/(q+x)-x are
// bit-identical to the passing rounds.

constexpr int K    = 512;
constexpr int D    = 64;
constexpr int NPTS = 16 * 4096;   // 65536

typedef __attribute__((ext_vector_type(8))) short  short8;
typedef __attribute__((ext_vector_type(4))) float  f32x4;

__device__ inline unsigned short bf16_rne(float f) {
    unsigned u = __builtin_bit_cast(unsigned, f);
    u += 0x7fffu + ((u >> 16) & 1u);
    return (unsigned short)(u >> 16);
}
__device__ inline float bf16_f32(unsigned short h) {
    unsigned u = (unsigned)h << 16;
    return __builtin_bit_cast(float, u);
}

// ---------------- pass 1: codebook prep (exact e2 + bf16 hi/lo split) ------
__global__ void prep_emb(const float* __restrict__ emb,
                         float* __restrict__ e2,
                         unsigned short* __restrict__ ehi,
                         unsigned short* __restrict__ elo)
{
    const int k = blockIdx.x * 64 + threadIdx.x;   // 8 blocks x 64 threads
    const float4* row = reinterpret_cast<const float4*>(emb + k * D);
    float v[64];
    #pragma unroll
    for (int i = 0; i < 16; ++i) {
        float4 q = row[i];
        v[4*i+0] = q.x; v[4*i+1] = q.y; v[4*i+2] = q.z; v[4*i+3] = q.w;
    }
    // exact sequential unfused e2 chain (same order as rounds 1-4)
    float s = 0.0f;
    {
        #pragma clang fp contract(off)
        #pragma unroll
        for (int d = 0; d < 64; ++d) s = s + v[d] * v[d];
    }
    e2[k] = s;
    #pragma unroll
    for (int d = 0; d < 64; ++d) {
        unsigned short h = bf16_rne(v[d]);
        float r = v[d] - bf16_f32(h);       // exact (Sterbenz)
        ehi[k*64 + d] = h;
        elo[k*64 + d] = bf16_rne(r);
    }
}

// ---------------- pass 2: MFMA argmin + gather ------------------------------
// Wave = 16 points x all 512 codes. D-tile: row=code=(lane>>4)*4+reg,
// col=point=lane&15 (m89-verified C/D layout). A = e (codes x k),
// B = x (k x points); lane holds 8 k-elems at k=(lane>>4)*8.
__global__ __launch_bounds__(256, 4)
void vq_mfma(const float* __restrict__ z,
             const float* __restrict__ emb,
             const float* __restrict__ e2,
             const unsigned short* __restrict__ ehi,
             const unsigned short* __restrict__ elo,
             float* __restrict__ out)
{
    const int tid = threadIdx.x;
    const int w   = tid >> 6;
    const int l   = tid & 63;
    const int col = l & 15;          // point within wave tile
    const int kg  = l >> 4;          // k-group / row-group

    const int pt0 = blockIdx.x * 64 + w * 16;

    const float4* zf4 = reinterpret_cast<const float4*>(z);
    const float4* ef4 = reinterpret_cast<const float4*>(emb);
    float4*       of4 = reinterpret_cast<float4*>(out);

    // exact sequential x2 for this lane's column point (same chain as R1-R4)
    float x2v = 0.0f;
    {
        #pragma clang fp contract(off)
        #pragma unroll
        for (int i = 0; i < 16; ++i) {
            float4 q = zf4[(pt0 + col) * 16 + i];
            x2v = x2v + q.x * q.x;
            x2v = x2v + q.y * q.y;
            x2v = x2v + q.z * q.z;
            x2v = x2v + q.w * q.w;
        }
    }

    // B-frags in registers: x[col][kt*32 + kg*8 + e], split bf16 hi/lo.
    short8 bh[2], bl[2];
    #pragma unroll
    for (int kt = 0; kt < 2; ++kt) {
        const float4 va = zf4[(pt0 + col) * 16 + kt * 8 + kg * 2];
        const float4 vb = zf4[(pt0 + col) * 16 + kt * 8 + kg * 2 + 1];
        const float xs[8] = {va.x, va.y, va.z, va.w, vb.x, vb.y, vb.z, vb.w};
        #pragma unroll
        for (int e = 0; e < 8; ++e) {          // static indices only
            const unsigned short h = bf16_rne(xs[e]);
            const float r = xs[e] - bf16_f32(h);   // exact
            bh[kt][e] = (short)h;
            bl[kt][e] = (short)bf16_rne(r);
        }
    }

    float bestv = INFINITY;
    int   besti = 0;

    #pragma unroll 2
    for (int t = 0; t < K / 16; ++t) {        // 32 code tiles
        const int arow = t * 16 + col;        // A row = code
        f32x4 acc = {0.f, 0.f, 0.f, 0.f};
        #pragma unroll
        for (int kt = 0; kt < 2; ++kt) {
            const short8 ah = *reinterpret_cast<const short8*>(ehi + arow * 64 + kt * 32 + kg * 8);
            const short8 al = *reinterpret_cast<const short8*>(elo + arow * 64 + kt * 32 + kg * 8);
            // small terms first, then dominant
            acc = __builtin_amdgcn_mfma_f32_16x16x32_bf16(al, bh[kt], acc, 0, 0, 0);
            acc = __builtin_amdgcn_mfma_f32_16x16x32_bf16(ah, bl[kt], acc, 0, 0, 0);
            acc = __builtin_amdgcn_mfma_f32_16x16x32_bf16(ah, bh[kt], acc, 0, 0, 0);
        }
        const int rbase = t * 16 + kg * 4;    // this lane's 4 code rows
        const float4 e2v = *reinterpret_cast<const float4*>(e2 + rbase);
        float dt;
        dt = (x2v - 2.0f * acc[0]) + e2v.x; if (dt < bestv) { bestv = dt; besti = rbase + 0; }
        dt = (x2v - 2.0f * acc[1]) + e2v.y; if (dt < bestv) { bestv = dt; besti = rbase + 1; }
        dt = (x2v - 2.0f * acc[2]) + e2v.z; if (dt < bestv) { bestv = dt; besti = rbase + 2; }
        dt = (x2v - 2.0f * acc[3]) + e2v.w; if (dt < bestv) { bestv = dt; besti = rbase + 3; }
    }

    // combine the 4 row-groups (lanes l, l^16, l^32, l^48 share a column):
    // lexicographic (dist, idx) -> global first-index argmin
    #pragma unroll
    for (int off = 16; off < 64; off <<= 1) {
        const float ov = __shfl_xor(bestv, off);
        const int   oi = __shfl_xor(besti, off);
        if (ov < bestv || (ov == bestv && oi < besti)) { bestv = ov; besti = oi; }
    }

    // epilogue: wave writes its 16 points x 64 dims, lane-linear coalesced
    #pragma unroll
    for (int i = 0; i < 4; ++i) {
        const int f4idx = i * 64 + l;     // 0..255 within wave region
        const int p = f4idx >> 4;         // local point 0..15
        const int j = f4idx & 15;
        const int qi = __shfl(besti, p);  // lane p holds col==p result
        const float4 q  = ef4[qi * 16 + j];
        const float4 xq = zf4[(pt0 + p) * 16 + j];
        float4 o;
        o.x = (q.x + xq.x) - xq.x;
        o.y = (q.y + xq.y) - xq.y;
        o.z = (q.z + xq.z) - xq.z;
        o.w = (q.w + xq.w) - xq.w;
        of4[(pt0 + p) * 16 + j] = o;
    }
}

extern "C" void kernel_launch(void* const* d_in, const int* in_sizes, int n_in,
                              void* d_out, int out_size, void* d_ws, size_t ws_size,
                              hipStream_t stream) {
    const float* z   = (const float*)d_in[0];
    const float* emb = (const float*)d_in[1];
    float* out = (float*)d_out;

    // workspace: e2 f32[512] | ehi bf16[512*64] | elo bf16[512*64]  (~130 KB)
    float*          e2  = (float*)d_ws;
    unsigned short* ehi = (unsigned short*)((char*)d_ws + 2048);
    unsigned short* elo = (unsigned short*)((char*)d_ws + 2048 + K * D * 2);

    prep_emb<<<K / 64, 64, 0, stream>>>(emb, e2, ehi, elo);
    vq_mfma<<<NPTS / 64, 256, 0, stream>>>(z, emb, e2, ehi, elo, out);
}

// Round 7
// 38.684 us; speedup vs baseline: 3.2506x; 2.1433x over previous
//
#include <hip/hip_runtime.h>
#include <math.h>

// st_VQEmbedding via LDS-staged MFMA GEMM.
// z [65536,64] f32, emb [512,64] f32 -> out = emb[argmin_k (x2-2dot)+e2] with
// straight-through (q+x)-x. dot via bf16 2-term split MFMA (al*bh + ah*bl +
// ah*bh, fp32 accum) -- identical term order / chains / tie-break to the R5
// kernel that passed with absmax 0.0.
//
// R6/R7: R5 was latency-bound (MfmaUtil 6%, per-lane global A-loads, 2-deep
// pipeline). Now: codes pre-split into bf16 hi/lo stored in PRE-SWIZZLED
// LDS-image order (slot = code*8 + (s ^ (code&7))), staged chunk-wise
// (128 codes, 32KB) into double-buffered LDS via global_load_lds(16) --
// linear dest (rule: gload_lds writes lane-linear), swizzle applied on the
// ds_read side. Each A-load feeds 2 point-tiles (12 MFMA / 64B-lane read).
// R7 fixes R6's compile error: '#pragma clang fp' must start a compound stmt.

constexpr int K      = 512;
constexpr int D      = 64;
constexpr int NPTS   = 16 * 4096;    // 65536
constexpr int BLOCK  = 256;
constexpr int PPB    = 128;          // points per block (4 waves x 32)
constexpr int CHUNK  = 128;          // codes per LDS chunk
constexpr int NCHUNK = K / CHUNK;    // 4
constexpr int TPC    = CHUNK / 16;   // 8 code-tiles per chunk

typedef __attribute__((ext_vector_type(8))) short  short8;
typedef __attribute__((ext_vector_type(4))) float  f32x4;

__device__ inline unsigned short bf16_rne(float f) {
    unsigned u = __builtin_bit_cast(unsigned, f);
    u += 0x7fffu + ((u >> 16) & 1u);
    return (unsigned short)(u >> 16);
}
__device__ inline float bf16_f32(unsigned short h) {
    unsigned u = (unsigned)h << 16;
    return __builtin_bit_cast(float, u);
}

// ---- prep: e2 (exact chain) + bf16 hi/lo split, written pre-swizzled ------
// thread t: code k = t>>3, d-slot s = t&7 (d = s*8..s*8+7).
// ws slot index = (k>>7)*1024 + (k&127)*8 + (s ^ (k&7))  [16B granules]
__global__ void prep_emb(const float* __restrict__ emb,
                         float* __restrict__ e2,
                         short8* __restrict__ wsHi,
                         short8* __restrict__ wsLo)
{
    const int gid = blockIdx.x * 256 + threadIdx.x;   // 0..4095
    const int k = gid >> 3;
    const int s = gid & 7;

    const float4* row = reinterpret_cast<const float4*>(emb + k * D);
    float v[64];
    #pragma unroll
    for (int i = 0; i < 16; ++i) {
        float4 q = row[i];
        v[4*i+0] = q.x; v[4*i+1] = q.y; v[4*i+2] = q.z; v[4*i+3] = q.w;
    }
    if (s == 0) {   // exact sequential unfused e2 (same chain as R1-R5)
        float acc = 0.0f;
        {
            #pragma clang fp contract(off)
            #pragma unroll
            for (int d = 0; d < 64; ++d) acc = acc + v[d] * v[d];
        }
        e2[k] = acc;
    }
    short8 hi, lo;
    #pragma unroll
    for (int e = 0; e < 8; ++e) {
        const float f = v[s * 8 + e];
        const unsigned short h = bf16_rne(f);
        const float r = f - bf16_f32(h);          // exact (Sterbenz)
        hi[e] = (short)h;
        lo[e] = (short)bf16_rne(r);
    }
    const int slot = (k >> 7) * 1024 + (k & 127) * 8 + (s ^ (k & 7));
    wsHi[slot] = hi;
    wsLo[slot] = lo;
}

// ---- main: LDS-staged MFMA argmin + gather ---------------------------------
__global__ __launch_bounds__(BLOCK, 2)
void vq_mfma(const float* __restrict__ z,
             const float* __restrict__ emb,
             const float* __restrict__ e2,
             const short8* __restrict__ wsHi,
             const short8* __restrict__ wsLo,
             float* __restrict__ out)
{
    __shared__ short8 Ahi[2][1024];   // 2 x 16 KiB
    __shared__ short8 Alo[2][1024];   // 2 x 16 KiB
    __shared__ int    bidx_s[PPB];

    const int tid = threadIdx.x;
    const int w   = tid >> 6;
    const int l   = tid & 63;
    const int col = l & 15;           // point within tile
    const int kg  = l >> 4;           // k-group / code-row group

    const float4* zf4 = reinterpret_cast<const float4*>(z);
    const float4* ef4 = reinterpret_cast<const float4*>(emb);
    float4*       of4 = reinterpret_cast<float4*>(out);

    const int base = blockIdx.x * PPB;
    const int pt0  = base + w * 32;

    // stage chunk c (128 codes, hi+lo) into buffer b: pure linear copy,
    // source is already in LDS-image (swizzled) order.
    auto stage = [&](int c, int b) {
        const short8* sH = wsHi + c * 1024;
        const short8* sL = wsLo + c * 1024;
        #pragma unroll
        for (int i = 0; i < 4; ++i) {
            const int f = i * 256 + tid;
            __builtin_amdgcn_global_load_lds(
                (const __attribute__((address_space(1))) void*)(sH + f),
                (__attribute__((address_space(3))) void*)&Ahi[b][f], 16, 0, 0);
            __builtin_amdgcn_global_load_lds(
                (const __attribute__((address_space(1))) void*)(sL + f),
                (__attribute__((address_space(3))) void*)&Alo[b][f], 16, 0, 0);
        }
    };

    stage(0, 0);   // in flight during x2 / B-frag build

    // ---- per-lane x2 (exact chain) + B-frags for 2 point-tiles ----
    float  x2v[2];
    short8 bh[2][2], bl[2][2];
    #pragma unroll
    for (int p = 0; p < 2; ++p) {
        const int pt = pt0 + p * 16 + col;
        float s = 0.0f;
        {
            #pragma clang fp contract(off)
            #pragma unroll
            for (int i = 0; i < 16; ++i) {
                float4 q = zf4[pt * 16 + i];
                s = s + q.x * q.x;
                s = s + q.y * q.y;
                s = s + q.z * q.z;
                s = s + q.w * q.w;
            }
        }
        x2v[p] = s;
        #pragma unroll
        for (int kt = 0; kt < 2; ++kt) {
            const float4 va = zf4[pt * 16 + kt * 8 + kg * 2];
            const float4 vb = zf4[pt * 16 + kt * 8 + kg * 2 + 1];
            const float xs[8] = {va.x, va.y, va.z, va.w, vb.x, vb.y, vb.z, vb.w};
            #pragma unroll
            for (int e = 0; e < 8; ++e) {
                const unsigned short h = bf16_rne(xs[e]);
                const float r = xs[e] - bf16_f32(h);   // exact
                bh[p][kt][e] = (short)h;
                bl[p][kt][e] = (short)bf16_rne(r);
            }
        }
    }

    __syncthreads();   // chunk 0 staged

    float best0 = INFINITY, best1 = INFINITY;
    int   bi0 = 0, bi1 = 0;
    int   b = 0;

    for (int c = 0; c < NCHUNK; ++c) {
        if (c + 1 < NCHUNK) stage(c + 1, b ^ 1);

        #pragma unroll
        for (int t = 0; t < TPC; ++t) {
            // swizzled A slots: code_local = t*16+col, sidx = (kt*4+kg)^(col&7)
            const int slot0 = ((t * 16 + col) << 3) | (kg ^ (col & 7)); // kt=0
            const short8 ah0 = Ahi[b][slot0];
            const short8 ah1 = Ahi[b][slot0 ^ 4];                        // kt=1
            const short8 al0 = Alo[b][slot0];
            const short8 al1 = Alo[b][slot0 ^ 4];

            f32x4 acc0 = {0.f, 0.f, 0.f, 0.f};
            f32x4 acc1 = {0.f, 0.f, 0.f, 0.f};
            // same term order as R5: per kt {al*bh, ah*bl, ah*bh}, kt0 then kt1
            acc0 = __builtin_amdgcn_mfma_f32_16x16x32_bf16(al0, bh[0][0], acc0, 0, 0, 0);
            acc0 = __builtin_amdgcn_mfma_f32_16x16x32_bf16(ah0, bl[0][0], acc0, 0, 0, 0);
            acc0 = __builtin_amdgcn_mfma_f32_16x16x32_bf16(ah0, bh[0][0], acc0, 0, 0, 0);
            acc0 = __builtin_amdgcn_mfma_f32_16x16x32_bf16(al1, bh[0][1], acc0, 0, 0, 0);
            acc0 = __builtin_amdgcn_mfma_f32_16x16x32_bf16(ah1, bl[0][1], acc0, 0, 0, 0);
            acc0 = __builtin_amdgcn_mfma_f32_16x16x32_bf16(ah1, bh[0][1], acc0, 0, 0, 0);

            acc1 = __builtin_amdgcn_mfma_f32_16x16x32_bf16(al0, bh[1][0], acc1, 0, 0, 0);
            acc1 = __builtin_amdgcn_mfma_f32_16x16x32_bf16(ah0, bl[1][0], acc1, 0, 0, 0);
            acc1 = __builtin_amdgcn_mfma_f32_16x16x32_bf16(ah0, bh[1][0], acc1, 0, 0, 0);
            acc1 = __builtin_amdgcn_mfma_f32_16x16x32_bf16(al1, bh[1][1], acc1, 0, 0, 0);
            acc1 = __builtin_amdgcn_mfma_f32_16x16x32_bf16(ah1, bl[1][1], acc1, 0, 0, 0);
            acc1 = __builtin_amdgcn_mfma_f32_16x16x32_bf16(ah1, bh[1][1], acc1, 0, 0, 0);

            const int   kbase = c * CHUNK + t * 16 + kg * 4;
            const float4 e2v  = *reinterpret_cast<const float4*>(e2 + kbase);
            float dt;
            dt = (x2v[0] - 2.0f * acc0[0]) + e2v.x; if (dt < best0) { best0 = dt; bi0 = kbase + 0; }
            dt = (x2v[0] - 2.0f * acc0[1]) + e2v.y; if (dt < best0) { best0 = dt; bi0 = kbase + 1; }
            dt = (x2v[0] - 2.0f * acc0[2]) + e2v.z; if (dt < best0) { best0 = dt; bi0 = kbase + 2; }
            dt = (x2v[0] - 2.0f * acc0[3]) + e2v.w; if (dt < best0) { best0 = dt; bi0 = kbase + 3; }
            dt = (x2v[1] - 2.0f * acc1[0]) + e2v.x; if (dt < best1) { best1 = dt; bi1 = kbase + 0; }
            dt = (x2v[1] - 2.0f * acc1[1]) + e2v.y; if (dt < best1) { best1 = dt; bi1 = kbase + 1; }
            dt = (x2v[1] - 2.0f * acc1[2]) + e2v.z; if (dt < best1) { best1 = dt; bi1 = kbase + 2; }
            dt = (x2v[1] - 2.0f * acc1[3]) + e2v.w; if (dt < best1) { best1 = dt; bi1 = kbase + 3; }
        }
        __syncthreads();   // drains stage vmcnt + all waves done with buf b
        b ^= 1;
    }

    // combine 4 kg-groups (lanes sharing a column): lexicographic (dist, idx)
    #pragma unroll
    for (int off = 16; off < 64; off <<= 1) {
        float ov = __shfl_xor(best0, off);
        int   oi = __shfl_xor(bi0,   off);
        if (ov < best0 || (ov == best0 && oi < bi0)) { best0 = ov; bi0 = oi; }
        ov = __shfl_xor(best1, off);
        oi = __shfl_xor(bi1,   off);
        if (ov < best1 || (ov == best1 && oi < bi1)) { best1 = ov; bi1 = oi; }
    }
    if (l < 16) {
        bidx_s[w * 32 + col]      = bi0;
        bidx_s[w * 32 + 16 + col] = bi1;
    }
    __syncthreads();

    // dense epilogue: lane-linear float4 stores, straight-through (q+x)-x
    #pragma unroll
    for (int i = 0; i < (PPB * 16) / BLOCK; ++i) {   // 8 iters
        const int idx = i * BLOCK + tid;
        const int p   = idx >> 4;
        const int j   = idx & 15;
        const float4 q = ef4[bidx_s[p] * 16 + j];
        const float4 x = zf4[(base + p) * 16 + j];
        float4 o;
        o.x = (q.x + x.x) - x.x;
        o.y = (q.y + x.y) - x.y;
        o.z = (q.z + x.z) - x.z;
        o.w = (q.w + x.w) - x.w;
        of4[(base + p) * 16 + j] = o;
    }
}

extern "C" void kernel_launch(void* const* d_in, const int* in_sizes, int n_in,
                              void* d_out, int out_size, void* d_ws, size_t ws_size,
                              hipStream_t stream) {
    const float* z   = (const float*)d_in[0];
    const float* emb = (const float*)d_in[1];
    float* out = (float*)d_out;

    // ws: e2 f32[512] (2KB) | wsHi short8[4096] (64KB) | wsLo short8[4096] (64KB)
    float*  e2   = (float*)d_ws;
    short8* wsHi = (short8*)((char*)d_ws + 2048);
    short8* wsLo = (short8*)((char*)d_ws + 2048 + 65536);

    prep_emb<<<16, 256, 0, stream>>>(emb, e2, wsHi, wsLo);
    vq_mfma<<<NPTS / PPB, BLOCK, 0, stream>>>(z, emb, e2, wsHi, wsLo, out);
}

// Round 8
// 37.365 us; speedup vs baseline: 3.3653x; 1.0353x over previous
//
#include <hip/hip_runtime.h>
#include <math.h>

// st_VQEmbedding via LDS-staged MFMA GEMM.
// z [65536,64] f32, emb [512,64] f32 -> out = emb[argmin_k (x2-2dot)+e2] with
// straight-through (q+x)-x. dot via bf16 2-term split MFMA (al*bh + ah*bl +
// ah*bh, fp32 accum) -- identical term order / chains / tie-break to the
// R5/R7 kernels that passed with absmax 0.0.
//
// R8: R7 was stall-bound at 2 blocks/CU (2 waves/SIMD; long per-tile dep
// chains exposed). CHUNK 128->64 cuts LDS 64->32KB => 4 blocks/CU (4 waves/
// SIMD). e2 staged in LDS once per block (kills per-tile L2 round-trips).
// Same pre-swizzled ws image (now 512-granule chunks), same arithmetic.

constexpr int K      = 512;
constexpr int D      = 64;
constexpr int NPTS   = 16 * 4096;    // 65536
constexpr int BLOCK  = 256;
constexpr int PPB    = 128;          // points per block (4 waves x 32)
constexpr int CHUNK  = 64;           // codes per LDS chunk
constexpr int NCHUNK = K / CHUNK;    // 8
constexpr int TPC    = CHUNK / 16;   // 4 code-tiles per chunk
constexpr int GPC    = CHUNK * 8;    // 512 16B-granules per chunk per array

typedef __attribute__((ext_vector_type(8))) short  short8;
typedef __attribute__((ext_vector_type(4))) float  f32x4;

__device__ inline unsigned short bf16_rne(float f) {
    unsigned u = __builtin_bit_cast(unsigned, f);
    u += 0x7fffu + ((u >> 16) & 1u);
    return (unsigned short)(u >> 16);
}
__device__ inline float bf16_f32(unsigned short h) {
    unsigned u = (unsigned)h << 16;
    return __builtin_bit_cast(float, u);
}

// ---- prep: e2 (exact chain) + bf16 hi/lo split, written pre-swizzled ------
// thread t: code k = t>>3, d-slot s = t&7 (d = s*8..s*8+7).
// ws granule index = (k>>6)*GPC + (k&63)*8 + (s ^ (k&7))
__global__ void prep_emb(const float* __restrict__ emb,
                         float* __restrict__ e2,
                         short8* __restrict__ wsHi,
                         short8* __restrict__ wsLo)
{
    const int gid = blockIdx.x * 256 + threadIdx.x;   // 0..4095
    const int k = gid >> 3;
    const int s = gid & 7;

    const float4* row = reinterpret_cast<const float4*>(emb + k * D);
    float v[64];
    #pragma unroll
    for (int i = 0; i < 16; ++i) {
        float4 q = row[i];
        v[4*i+0] = q.x; v[4*i+1] = q.y; v[4*i+2] = q.z; v[4*i+3] = q.w;
    }
    if (s == 0) {   // exact sequential unfused e2 (same chain as R1-R7)
        float acc = 0.0f;
        {
            #pragma clang fp contract(off)
            #pragma unroll
            for (int d = 0; d < 64; ++d) acc = acc + v[d] * v[d];
        }
        e2[k] = acc;
    }
    short8 hi, lo;
    #pragma unroll
    for (int e = 0; e < 8; ++e) {
        const float f = v[s * 8 + e];
        const unsigned short h = bf16_rne(f);
        const float r = f - bf16_f32(h);          // exact (Sterbenz)
        hi[e] = (short)h;
        lo[e] = (short)bf16_rne(r);
    }
    const int slot = (k >> 6) * GPC + (k & 63) * 8 + (s ^ (k & 7));
    wsHi[slot] = hi;
    wsLo[slot] = lo;
}

// ---- main: LDS-staged MFMA argmin + gather ---------------------------------
__global__ __launch_bounds__(BLOCK, 4)
void vq_mfma(const float* __restrict__ z,
             const float* __restrict__ emb,
             const float* __restrict__ e2,
             const short8* __restrict__ wsHi,
             const short8* __restrict__ wsLo,
             float* __restrict__ out)
{
    __shared__ short8 Ahi[2][GPC];    // 2 x 8 KiB
    __shared__ short8 Alo[2][GPC];    // 2 x 8 KiB
    __shared__ float4 e2L[K / 4];     // 2 KiB
    __shared__ int    bidx_s[PPB];

    const int tid = threadIdx.x;
    const int w   = tid >> 6;
    const int l   = tid & 63;
    const int col = l & 15;           // point within tile
    const int kg  = l >> 4;           // k-group / code-row group

    const float4* zf4 = reinterpret_cast<const float4*>(z);
    const float4* ef4 = reinterpret_cast<const float4*>(emb);
    float4*       of4 = reinterpret_cast<float4*>(out);

    const int base = blockIdx.x * PPB;
    const int pt0  = base + w * 32;

    // stage chunk c (64 codes, hi+lo) into buffer b: pure linear copy,
    // source already in LDS-image (swizzled) order.
    auto stage = [&](int c, int b) {
        const short8* sH = wsHi + c * GPC;
        const short8* sL = wsLo + c * GPC;
        #pragma unroll
        for (int i = 0; i < 2; ++i) {
            const int f = i * 256 + tid;
            __builtin_amdgcn_global_load_lds(
                (const __attribute__((address_space(1))) void*)(sH + f),
                (__attribute__((address_space(3))) void*)&Ahi[b][f], 16, 0, 0);
            __builtin_amdgcn_global_load_lds(
                (const __attribute__((address_space(1))) void*)(sL + f),
                (__attribute__((address_space(3))) void*)&Alo[b][f], 16, 0, 0);
        }
    };

    stage(0, 0);   // in flight during x2 / B-frag build
    if (tid < K / 4) {   // e2 -> LDS, lane-linear 16B granules
        __builtin_amdgcn_global_load_lds(
            (const __attribute__((address_space(1))) void*)(e2 + tid * 4),
            (__attribute__((address_space(3))) void*)&e2L[tid], 16, 0, 0);
    }

    // ---- per-lane x2 (exact chain) + B-frags for 2 point-tiles ----
    float  x2v[2];
    short8 bh[2][2], bl[2][2];
    #pragma unroll
    for (int p = 0; p < 2; ++p) {
        const int pt = pt0 + p * 16 + col;
        float s = 0.0f;
        {
            #pragma clang fp contract(off)
            #pragma unroll
            for (int i = 0; i < 16; ++i) {
                float4 q = zf4[pt * 16 + i];
                s = s + q.x * q.x;
                s = s + q.y * q.y;
                s = s + q.z * q.z;
                s = s + q.w * q.w;
            }
        }
        x2v[p] = s;
        #pragma unroll
        for (int kt = 0; kt < 2; ++kt) {
            const float4 va = zf4[pt * 16 + kt * 8 + kg * 2];
            const float4 vb = zf4[pt * 16 + kt * 8 + kg * 2 + 1];
            const float xs[8] = {va.x, va.y, va.z, va.w, vb.x, vb.y, vb.z, vb.w};
            #pragma unroll
            for (int e = 0; e < 8; ++e) {
                const unsigned short h = bf16_rne(xs[e]);
                const float r = xs[e] - bf16_f32(h);   // exact
                bh[p][kt][e] = (short)h;
                bl[p][kt][e] = (short)bf16_rne(r);
            }
        }
    }

    __syncthreads();   // chunk 0 + e2L staged

    float best0 = INFINITY, best1 = INFINITY;
    int   bi0 = 0, bi1 = 0;
    int   b = 0;

    for (int c = 0; c < NCHUNK; ++c) {
        if (c + 1 < NCHUNK) stage(c + 1, b ^ 1);

        #pragma unroll
        for (int t = 0; t < TPC; ++t) {
            // swizzled A slots: code_local = t*16+col, sidx = (kt*4+kg)^(col&7)
            const int slot0 = ((t * 16 + col) << 3) | (kg ^ (col & 7)); // kt=0
            const short8 ah0 = Ahi[b][slot0];
            const short8 ah1 = Ahi[b][slot0 ^ 4];                        // kt=1
            const short8 al0 = Alo[b][slot0];
            const short8 al1 = Alo[b][slot0 ^ 4];

            f32x4 acc0 = {0.f, 0.f, 0.f, 0.f};
            f32x4 acc1 = {0.f, 0.f, 0.f, 0.f};
            // same term order as R5/R7: per kt {al*bh, ah*bl, ah*bh}, kt0,kt1
            acc0 = __builtin_amdgcn_mfma_f32_16x16x32_bf16(al0, bh[0][0], acc0, 0, 0, 0);
            acc0 = __builtin_amdgcn_mfma_f32_16x16x32_bf16(ah0, bl[0][0], acc0, 0, 0, 0);
            acc0 = __builtin_amdgcn_mfma_f32_16x16x32_bf16(ah0, bh[0][0], acc0, 0, 0, 0);
            acc0 = __builtin_amdgcn_mfma_f32_16x16x32_bf16(al1, bh[0][1], acc0, 0, 0, 0);
            acc0 = __builtin_amdgcn_mfma_f32_16x16x32_bf16(ah1, bl[0][1], acc0, 0, 0, 0);
            acc0 = __builtin_amdgcn_mfma_f32_16x16x32_bf16(ah1, bh[0][1], acc0, 0, 0, 0);

            acc1 = __builtin_amdgcn_mfma_f32_16x16x32_bf16(al0, bh[1][0], acc1, 0, 0, 0);
            acc1 = __builtin_amdgcn_mfma_f32_16x16x32_bf16(ah0, bl[1][0], acc1, 0, 0, 0);
            acc1 = __builtin_amdgcn_mfma_f32_16x16x32_bf16(ah0, bh[1][0], acc1, 0, 0, 0);
            acc1 = __builtin_amdgcn_mfma_f32_16x16x32_bf16(al1, bh[1][1], acc1, 0, 0, 0);
            acc1 = __builtin_amdgcn_mfma_f32_16x16x32_bf16(ah1, bl[1][1], acc1, 0, 0, 0);
            acc1 = __builtin_amdgcn_mfma_f32_16x16x32_bf16(ah1, bh[1][1], acc1, 0, 0, 0);

            const int   kbase = c * CHUNK + t * 16 + kg * 4;
            const float4 e2v  = e2L[kbase >> 2];   // broadcast-pattern ds_read
            float dt;
            dt = (x2v[0] - 2.0f * acc0[0]) + e2v.x; if (dt < best0) { best0 = dt; bi0 = kbase + 0; }
            dt = (x2v[0] - 2.0f * acc0[1]) + e2v.y; if (dt < best0) { best0 = dt; bi0 = kbase + 1; }
            dt = (x2v[0] - 2.0f * acc0[2]) + e2v.z; if (dt < best0) { best0 = dt; bi0 = kbase + 2; }
            dt = (x2v[0] - 2.0f * acc0[3]) + e2v.w; if (dt < best0) { best0 = dt; bi0 = kbase + 3; }
            dt = (x2v[1] - 2.0f * acc1[0]) + e2v.x; if (dt < best1) { best1 = dt; bi1 = kbase + 0; }
            dt = (x2v[1] - 2.0f * acc1[1]) + e2v.y; if (dt < best1) { best1 = dt; bi1 = kbase + 1; }
            dt = (x2v[1] - 2.0f * acc1[2]) + e2v.z; if (dt < best1) { best1 = dt; bi1 = kbase + 2; }
            dt = (x2v[1] - 2.0f * acc1[3]) + e2v.w; if (dt < best1) { best1 = dt; bi1 = kbase + 3; }
        }
        __syncthreads();   // drains stage vmcnt + all waves done with buf b
        b ^= 1;
    }

    // combine 4 kg-groups (lanes sharing a column): lexicographic (dist, idx)
    #pragma unroll
    for (int off = 16; off < 64; off <<= 1) {
        float ov = __shfl_xor(best0, off);
        int   oi = __shfl_xor(bi0,   off);
        if (ov < best0 || (ov == best0 && oi < bi0)) { best0 = ov; bi0 = oi; }
        ov = __shfl_xor(best1, off);
        oi = __shfl_xor(bi1,   off);
        if (ov < best1 || (ov == best1 && oi < bi1)) { best1 = ov; bi1 = oi; }
    }
    if (l < 16) {
        bidx_s[w * 32 + col]      = bi0;
        bidx_s[w * 32 + 16 + col] = bi1;
    }
    __syncthreads();

    // dense epilogue: lane-linear float4 stores, straight-through (q+x)-x
    #pragma unroll
    for (int i = 0; i < (PPB * 16) / BLOCK; ++i) {   // 8 iters
        const int idx = i * BLOCK + tid;
        const int p   = idx >> 4;
        const int j   = idx & 15;
        const float4 q = ef4[bidx_s[p] * 16 + j];
        const float4 x = zf4[(base + p) * 16 + j];
        float4 o;
        o.x = (q.x + x.x) - x.x;
        o.y = (q.y + x.y) - x.y;
        o.z = (q.z + x.z) - x.z;
        o.w = (q.w + x.w) - x.w;
        of4[(base + p) * 16 + j] = o;
    }
}

extern "C" void kernel_launch(void* const* d_in, const int* in_sizes, int n_in,
                              void* d_out, int out_size, void* d_ws, size_t ws_size,
                              hipStream_t stream) {
    const float* z   = (const float*)d_in[0];
    const float* emb = (const float*)d_in[1];
    float* out = (float*)d_out;

    // ws: e2 f32[512] (2KB) | wsHi short8[4096] (64KB) | wsLo short8[4096] (64KB)
    float*  e2   = (float*)d_ws;
    short8* wsHi = (short8*)((char*)d_ws + 2048);
    short8* wsLo = (short8*)((char*)d_ws + 2048 + 65536);

    prep_emb<<<16, 256, 0, stream>>>(emb, e2, wsHi, wsLo);
    vq_mfma<<<NPTS / PPB, BLOCK, 0, stream>>>(z, emb, e2, wsHi, wsLo, out);
}